// Round 1
// baseline (221.352 us; speedup 1.0000x reference)
//
#include <hip/hip_runtime.h>

// CovLayer: X [B=64, C=256, T=2048] fp32 -> cov [B, 256, 256] fp32
// Round 5: two-pass global split-K restructure.
//  Pass 1 (cov_gram): 256 blocks = 64 batches x 4 K-chunks (K=512). Each block
//    stages ONE 256x32 bf16 X-tile in LDS (Gram symmetry: A and B fragments
//    read the same tile) -> every X byte fetched from HBM exactly once
//    (134 MB vs ~537 MB with the old quadrant scheme). Writes f32 partial
//    Gram (64 MB) + partial row-sums to workspace.
//  Pass 2 (cov_reduce): streaming 4-way reduce + mean correction, f32x4 I/O.

#define NB 64
#define NC 256
#define NT 2048
#define NKC 4
#define KC (NT / NKC)      // 512 k per block
#define BK 32              // k per iteration
#define NIT (KC / BK)      // 16 iterations

#define G_STRIDE ((size_t)NB * NC * NC)   // floats per kc-slice of partial Gram
#define SX_OFF   ((size_t)NKC * G_STRIDE) // row-sum partials start here
#define SX_STRIDE (NB * NC)

typedef __bf16 bf16x8 __attribute__((ext_vector_type(8)));
typedef float  f32x8  __attribute__((ext_vector_type(8)));
typedef float  f32x4  __attribute__((ext_vector_type(4)));

__global__ __launch_bounds__(512, 2) void cov_gram(const float* __restrict__ X,
                                                   float* __restrict__ ws) {
    // Double-buffered single symmetric tile: [2][256 rows][32 k] bf16 = 32 KB.
    __shared__ __align__(16) __bf16 sX[2][NC * BK];

    const int bid = blockIdx.x;
    const int b   = bid >> 2;        // batch
    const int kc  = bid & 3;         // K-chunk
    const float* __restrict__ Xb = X + (size_t)b * (NC * NT) + kc * KC;

    const int t    = threadIdx.x;    // 512 threads = 8 waves
    const int lane = t & 63;
    const int wave = t >> 6;
    const int wm   = wave >> 2;      // 0..1: row-half (128 rows)
    const int wn   = wave & 3;       // 0..3: col-quarter (64 cols)
    const int quad = lane >> 4;
    const int l16  = lane & 15;

    // Staging: thread t covers row sr, 16-float half sc. 2 threads/row.
    const int sr = t >> 1;
    const int sc = (t & 1) * 16;
    const float* g0 = Xb + (size_t)sr * NT + sc;
    const int woff = sr * BK + sc;

    f32x4 acc[8][4], accRS[2];
#pragma unroll
    for (int mt = 0; mt < 8; ++mt)
#pragma unroll
        for (int nt = 0; nt < 4; ++nt)
            acc[mt][nt] = (f32x4){0.f, 0.f, 0.f, 0.f};
    accRS[0] = (f32x4){0.f, 0.f, 0.f, 0.f};
    accRS[1] = (f32x4){0.f, 0.f, 0.f, 0.f};

    const bf16x8 ones = {(__bf16)1.0f, (__bf16)1.0f, (__bf16)1.0f, (__bf16)1.0f,
                         (__bf16)1.0f, (__bf16)1.0f, (__bf16)1.0f, (__bf16)1.0f};

    // Prologue: stage iter 0 into buf0; prefetch iter 1 into regs.
    f32x8 p0 = *(const f32x8*)g0;
    f32x8 p1 = *(const f32x8*)(g0 + 8);
    *(bf16x8*)&sX[0][woff]     = __builtin_convertvector(p0, bf16x8);
    *(bf16x8*)&sX[0][woff + 8] = __builtin_convertvector(p1, bf16x8);
    p0 = *(const f32x8*)(g0 + BK);
    p1 = *(const f32x8*)(g0 + BK + 8);
    __syncthreads();

    // Fragment bases (64-B rows: full-wave-contiguous 1KB reads, conflict-benign).
    const int aBase  = (wm * 128 + l16) * BK + quad * 8;      // + mt*16*BK
    const int bBase  = (wn * 64 + l16) * BK + quad * 8;       // + nt*16*BK
    // Row-sum fragments: wave (wm,wn) owns rows wm*128 + wn*32 .. +32.
    // (Dedicated ds_reads: indexing aF[2*wn] would scratch-spill — rule #20.)
    const int rsBase = (wm * 128 + wn * 32 + l16) * BK + quad * 8;

#pragma unroll 2
    for (int k = 0; k < NIT; ++k) {
        const int cur = k & 1, nxt = cur ^ 1;

        // Stage G_{k+1} (already in regs) into the other buffer.
        if (k + 1 < NIT) {
            *(bf16x8*)&sX[nxt][woff]     = __builtin_convertvector(p0, bf16x8);
            *(bf16x8*)&sX[nxt][woff + 8] = __builtin_convertvector(p1, bf16x8);
        }
        // Prefetch G_{k+2}: consumed one full iteration from now.
        if (k + 2 < NIT) {
            p0 = *(const f32x8*)(g0 + (k + 2) * BK);
            p1 = *(const f32x8*)(g0 + (k + 2) * BK + 8);
        }

        bf16x8 aF[8], bF[4];
#pragma unroll
        for (int mt = 0; mt < 8; ++mt)
            aF[mt] = *(const bf16x8*)&sX[cur][aBase + mt * 16 * BK];
#pragma unroll
        for (int nt = 0; nt < 4; ++nt)
            bF[nt] = *(const bf16x8*)&sX[cur][bBase + nt * 16 * BK];
        bf16x8 rF0 = *(const bf16x8*)&sX[cur][rsBase];
        bf16x8 rF1 = *(const bf16x8*)&sX[cur][rsBase + 16 * BK];

#pragma unroll
        for (int mt = 0; mt < 8; ++mt)
#pragma unroll
            for (int nt = 0; nt < 4; ++nt)
                acc[mt][nt] = __builtin_amdgcn_mfma_f32_16x16x32_bf16(
                    aF[mt], bF[nt], acc[mt][nt], 0, 0, 0);
        accRS[0] = __builtin_amdgcn_mfma_f32_16x16x32_bf16(rF0, ones, accRS[0], 0, 0, 0);
        accRS[1] = __builtin_amdgcn_mfma_f32_16x16x32_bf16(rF1, ones, accRS[1], 0, 0, 0);

        __syncthreads();   // one barrier per iteration (dbuf decouples the rest)
    }

    // Epilogue: write partial Gram + partial row-sums to workspace.
    float* __restrict__ Gp = ws + (size_t)kc * G_STRIDE + (size_t)b * (NC * NC);
#pragma unroll
    for (int mt = 0; mt < 8; ++mt) {
        const int i0 = wm * 128 + mt * 16 + quad * 4;
#pragma unroll
        for (int nt = 0; nt < 4; ++nt) {
            const int j = wn * 64 + nt * 16 + l16;
#pragma unroll
            for (int r = 0; r < 4; ++r)
                Gp[(size_t)(i0 + r) * NC + j] = acc[mt][nt][r];
        }
    }
    if (l16 == 0) {
        float* __restrict__ Sp = ws + SX_OFF + (size_t)kc * SX_STRIDE + b * NC;
#pragma unroll
        for (int s = 0; s < 2; ++s)
#pragma unroll
            for (int r = 0; r < 4; ++r)
                Sp[wm * 128 + wn * 32 + s * 16 + quad * 4 + r] = accRS[s][r];
    }
}

__global__ __launch_bounds__(256) void cov_reduce(const float* __restrict__ ws,
                                                  float* __restrict__ out) {
    // One f32x4 along j per thread. 4096 blocks x 256 threads = 64*256*64 quads.
    const unsigned e  = blockIdx.x * 256u + threadIdx.x;
    const int j4 = e & 63;
    const int i  = (e >> 6) & 255;
    const int b  = e >> 14;
    const size_t g = ((size_t)b * NC + i) * NC + j4 * 4;

    f32x4 s = *(const f32x4*)&ws[g];
    s += *(const f32x4*)&ws[G_STRIDE + g];
    s += *(const f32x4*)&ws[2 * G_STRIDE + g];
    s += *(const f32x4*)&ws[3 * G_STRIDE + g];

    const float* __restrict__ Sx = ws + SX_OFF;
    const int sb = b * NC;
    float sxi = Sx[sb + i] + Sx[SX_STRIDE + sb + i] +
                Sx[2 * SX_STRIDE + sb + i] + Sx[3 * SX_STRIDE + sb + i];
    f32x4 sy = *(const f32x4*)&Sx[sb + j4 * 4];
    sy += *(const f32x4*)&Sx[SX_STRIDE + sb + j4 * 4];
    sy += *(const f32x4*)&Sx[2 * SX_STRIDE + sb + j4 * 4];
    sy += *(const f32x4*)&Sx[3 * SX_STRIDE + sb + j4 * 4];

    const float invT = 1.0f / NT;
    f32x4 r = (s - sy * (sxi * invT)) * invT;
    *(f32x4*)&out[g] = r;
}

extern "C" void kernel_launch(void* const* d_in, const int* in_sizes, int n_in,
                              void* d_out, int out_size, void* d_ws, size_t ws_size,
                              hipStream_t stream) {
    const float* X = (const float*)d_in[0];
    float* out = (float*)d_out;
    float* ws = (float*)d_ws;
    (void)in_sizes; (void)n_in; (void)out_size; (void)ws_size;
    cov_gram<<<256, 512, 0, stream>>>(X, ws);
    cov_reduce<<<4096, 256, 0, stream>>>(ws, out);
}

// Round 2
// 207.556 us; speedup vs baseline: 1.0665x; 1.0665x over previous
//
#include <hip/hip_runtime.h>

// CovLayer: X [B=64, C=256, T=2048] fp32 -> cov [B, 256, 256] fp32
// Round 6: single-pass again (ws round-trip regressed: L3 was already
// absorbing re-reads). Exploit Gram symmetry: 3 blocks/batch instead of 4
// (diag quadrants read 1 MB each with A==B panel; off-diag block writes both
// (0,1) and (1,0)^T via LDS-transpose bounce through red[]). Cache demand
// 537 MB -> 268 MB; HBM fetch stays 134 MB. Batch's 3 blocks share an XCD.
// Microstructure unchanged from the 205 µs baseline: 512 thr = 8 waves,
// 2x2 spatial (64x64/wave) x in-block split-K 2, dbuf LDS, prefetch depth 2,
// one barrier/iter.

#define NB 64
#define NC 256
#define NT 2048
#define NITER 32        // (NT/2) / 32 per K-half

typedef __bf16 bf16x8 __attribute__((ext_vector_type(8)));
typedef float  f32x8  __attribute__((ext_vector_type(8)));
typedef float  f32x4  __attribute__((ext_vector_type(4)));

__global__ __launch_bounds__(512, 2) void cov_kernel(const float* __restrict__ X,
                                                     float* __restrict__ out) {
    // Staging: [A/B][buf 0/1][half 0/1][128*32 bf16]  = 64 KB.
    // Epilogue overlay: red[4][64*65] + rs[4*64] + cs[4*64] floats = 68.6 KB.
    __shared__ __align__(16) unsigned char smem[68608];
    __bf16* sAB  = (__bf16*)smem;
    float*  redF = (float*)smem;

    const int bid  = blockIdx.x;          // 192 blocks
    const int xcd  = bid & 7;
    const int g    = bid >> 3;            // 0..23
    const int b    = xcd + 8 * (g / 3);   // a batch's 3 blocks share an XCD
    const int qi   = g % 3;               // 0:(0,0)  1:(1,1)  2:(0,1)+(1,0)^T
    const int row0 = (qi == 1) ? 128 : 0;
    const int col0 = (qi == 0) ? 0 : 128;
    const bool diag = (qi != 2);

    const float* __restrict__ Xb = X + (size_t)b * (NC * NT);

    const int t    = threadIdx.x;        // 512 threads = 8 waves
    const int lane = t & 63;
    const int wave = t >> 6;
    const int h    = wave >> 2;          // K-half: [h*1024, h*1024+1024)
    const int wq   = wave & 3;
    const int wm   = wq >> 1, wn = wq & 1;   // 2x2 waves, 64x64 each
    const int quad = lane >> 4;
    const int l16  = lane & 15;

    // Staging: u = t&255 within half h. Thread u: rows sr and sr+64, k-chunk sc.
    const int u  = t & 255;
    const int sr = u >> 2;               // 0..63
    const int sc = (u & 3) * 8;          // 4 lanes cover 32 contiguous floats/row
    const float* gA0 = Xb + (size_t)(row0 + sr) * NT + h * (NT / 2) + sc;
    const float* gA1 = gA0 + (size_t)64 * NT;
    const float* gB0 = Xb + (size_t)(col0 + sr) * NT + h * (NT / 2) + sc;
    const float* gB1 = gB0 + (size_t)64 * NT;

    // LDS staging bases (elements) for this thread's half.
    __bf16* sA[2] = { sAB + (0 * 2 + h) * 4096, sAB + (1 * 2 + h) * 4096 };
    __bf16* sB[2];
    if (diag) { sB[0] = sA[0]; sB[1] = sA[1]; }     // B-panel == A-panel
    else {
        sB[0] = sAB + 16384 + (0 * 2 + h) * 4096;
        sB[1] = sAB + 16384 + (1 * 2 + h) * 4096;
    }
    const int woff = sr * 32 + sc;       // write offset; second row at +2048

    f32x4 acc[4][4], accRS[4], accCS[4];
#pragma unroll
    for (int i = 0; i < 4; ++i) {
        accRS[i] = (f32x4){0.f, 0.f, 0.f, 0.f};
        accCS[i] = (f32x4){0.f, 0.f, 0.f, 0.f};
#pragma unroll
        for (int j = 0; j < 4; ++j) acc[i][j] = (f32x4){0.f, 0.f, 0.f, 0.f};
    }
    const bf16x8 ones = {(__bf16)1.0f, (__bf16)1.0f, (__bf16)1.0f, (__bf16)1.0f,
                         (__bf16)1.0f, (__bf16)1.0f, (__bf16)1.0f, (__bf16)1.0f};

    // Prologue: stage iter 0 into buf0, prefetch iter 1 into regs.
    f32x8 pA0 = *(const f32x8*)gA0;
    f32x8 pA1 = *(const f32x8*)gA1;
    f32x8 pB0 = pA0, pB1 = pA1;
    if (!diag) { pB0 = *(const f32x8*)gB0; pB1 = *(const f32x8*)gB1; }
    *(bf16x8*)(sA[0] + woff)        = __builtin_convertvector(pA0, bf16x8);
    *(bf16x8*)(sA[0] + woff + 2048) = __builtin_convertvector(pA1, bf16x8);
    if (!diag) {
        *(bf16x8*)(sB[0] + woff)        = __builtin_convertvector(pB0, bf16x8);
        *(bf16x8*)(sB[0] + woff + 2048) = __builtin_convertvector(pB1, bf16x8);
    }
    pA0 = *(const f32x8*)(gA0 + 32);
    pA1 = *(const f32x8*)(gA1 + 32);
    if (!diag) {
        pB0 = *(const f32x8*)(gB0 + 32);
        pB1 = *(const f32x8*)(gB1 + 32);
    }
    __syncthreads();

    const int aBase = (wm * 64 + l16) * 32 + quad * 8;   // + mt*16*32
    const int bBase = (wn * 64 + l16) * 32 + quad * 8;

#pragma unroll 2
    for (int k = 0; k < NITER; ++k) {
        const int cur = k & 1, nxt = cur ^ 1;

        // Stage G_{k+1} (in regs) into the other buffer; its last readers
        // finished before the barrier that ended iteration k-1.
        if (k + 1 < NITER) {
            *(bf16x8*)(sA[nxt] + woff)        = __builtin_convertvector(pA0, bf16x8);
            *(bf16x8*)(sA[nxt] + woff + 2048) = __builtin_convertvector(pA1, bf16x8);
            if (!diag) {
                *(bf16x8*)(sB[nxt] + woff)        = __builtin_convertvector(pB0, bf16x8);
                *(bf16x8*)(sB[nxt] + woff + 2048) = __builtin_convertvector(pB1, bf16x8);
            }
        }
        // Prefetch G_{k+2}: consumed one full iteration from now.
        if (k + 2 < NITER) {
            pA0 = *(const f32x8*)(gA0 + (k + 2) * 32);
            pA1 = *(const f32x8*)(gA1 + (k + 2) * 32);
            if (!diag) {
                pB0 = *(const f32x8*)(gB0 + (k + 2) * 32);
                pB1 = *(const f32x8*)(gB1 + (k + 2) * 32);
            }
        }

        bf16x8 aF[4], bF[4];
#pragma unroll
        for (int mt = 0; mt < 4; ++mt)
            aF[mt] = *(const bf16x8*)(sA[cur] + aBase + mt * 16 * 32);
#pragma unroll
        for (int nt = 0; nt < 4; ++nt)
            bF[nt] = *(const bf16x8*)(sB[cur] + bBase + nt * 16 * 32);

#pragma unroll
        for (int mt = 0; mt < 4; ++mt) {
            accRS[mt] = __builtin_amdgcn_mfma_f32_16x16x32_bf16(aF[mt], ones, accRS[mt], 0, 0, 0);
#pragma unroll
            for (int nt = 0; nt < 4; ++nt)
                acc[mt][nt] = __builtin_amdgcn_mfma_f32_16x16x32_bf16(aF[mt], bF[nt], acc[mt][nt], 0, 0, 0);
        }
#pragma unroll
        for (int nt = 0; nt < 4; ++nt)
            accCS[nt] = __builtin_amdgcn_mfma_f32_16x16x32_bf16(ones, bF[nt], accCS[nt], 0, 0, 0);

        __syncthreads();   // one barrier per iteration (dbuf decouples the rest)
    }

    // Epilogue: combine the two K-halves. h=1 dumps to LDS; h=0 reduces+stores.
    float* red = redF + wq * (64 * 65);
    float* rs  = redF + 4 * (64 * 65);       // [4][64]
    float* cs  = rs + 256;                   // [4][64]

    if (h == 1) {
#pragma unroll
        for (int mt = 0; mt < 4; ++mt)
#pragma unroll
            for (int nt = 0; nt < 4; ++nt)
#pragma unroll
                for (int r = 0; r < 4; ++r)
                    red[(mt * 16 + quad * 4 + r) * 65 + nt * 16 + l16] = acc[mt][nt][r];
        if (l16 == 0) {
#pragma unroll
            for (int mt = 0; mt < 4; ++mt)
#pragma unroll
                for (int r = 0; r < 4; ++r)
                    rs[wq * 64 + mt * 16 + quad * 4 + r] = accRS[mt][r];
        }
        if (quad == 0) {
#pragma unroll
            for (int nt = 0; nt < 4; ++nt)
                cs[wq * 64 + nt * 16 + l16] = accCS[nt][0];
        }
    }
    __syncthreads();

    const float invT = 1.0f / NT;
    float* __restrict__ outB = out + (size_t)b * (NC * NC);

    if (h == 0) {
#pragma unroll
        for (int mt = 0; mt < 4; ++mt) {
#pragma unroll
            for (int nt = 0; nt < 4; ++nt) {
#pragma unroll
                for (int r = 0; r < 4; ++r) {
                    const int R = mt * 16 + quad * 4 + r;
                    const int C = nt * 16 + l16;
                    const float tot = red[R * 65 + C] + acc[mt][nt][r];
                    const float Sx  = rs[wq * 64 + R] + accRS[mt][r];
                    const float Sy  = cs[wq * 64 + C] + accCS[nt][0];
                    const float val = (tot - Sx * Sy * invT) * invT;
                    outB[(size_t)(row0 + wm * 64 + R) * NC + (col0 + wn * 64 + C)] = val;
                    if (qi == 2) red[R * 65 + C] = val;   // park for transpose
                }
            }
        }
    }

    if (qi == 2) {
        // Mirror the corrected tile into quadrant (1,0): out[col][row] = val.
        __syncthreads();
        if (h == 1) {
#pragma unroll
            for (int mt = 0; mt < 4; ++mt) {
                const int jj = mt * 16 + quad * 4;       // + r
#pragma unroll
                for (int nt = 0; nt < 4; ++nt) {
                    const int ii = nt * 16 + l16;
#pragma unroll
                    for (int r = 0; r < 4; ++r)
                        outB[(size_t)(col0 + wn * 64 + jj + r) * NC +
                             (row0 + wm * 64 + ii)] = red[ii * 65 + jj + r];
                }
            }
        }
    }
}

extern "C" void kernel_launch(void* const* d_in, const int* in_sizes, int n_in,
                              void* d_out, int out_size, void* d_ws, size_t ws_size,
                              hipStream_t stream) {
    const float* X = (const float*)d_in[0];
    float* out = (float*)d_out;
    (void)in_sizes; (void)n_in; (void)out_size; (void)d_ws; (void)ws_size;
    cov_kernel<<<192, 512, 0, stream>>>(X, out);
}

// Round 5
// 207.554 us; speedup vs baseline: 1.0665x; 1.0000x over previous
//
#include <hip/hip_runtime.h>

// CovLayer: X [B=64, C=256, T=2048] fp32 -> cov [B, 256, 256] fp32
// Round 9: same latency theory as r7/r8 (per-iter vmcnt(0) drain at
// __syncthreads exposes contended HBM latency: 3260 cyc/iter vs ~500 cyc
// work, perf insensitive to cache demand). The r7/r8 all-in-one inline-asm
// barrier ("s_waitcnt lgkmcnt(0)\n s_barrier" in ONE asm) is the prime
// suspect for the two container deaths: an asm s_barrier is invisible to
// convergence analysis and can be duplicated under unroll+guards -> wave
// barrier-count mismatch -> wedge. This round uses only hardware-proven
// components (m201 template form): sched_barrier(0) pin + single-instruction
// waitcnt asm + __builtin_amdgcn_s_barrier() (compiler-known, convergent).
// Structure = round 6 (ran fine): 192 blocks, 3/batch Gram symmetry,
// 8 waves = 2x2 spatial x split-K 2, dbuf LDS, one barrier/iter,
// two-set (p,q) register prefetch so staged data is 2 iterations old.

#define NB 64
#define NC 256
#define NT 2048
#define NITER 32        // (NT/2) / 32 per K-half

typedef __bf16 bf16x8 __attribute__((ext_vector_type(8)));
typedef float  f32x8  __attribute__((ext_vector_type(8)));
typedef float  f32x4  __attribute__((ext_vector_type(4)));

// LDS-visibility barrier that does NOT drain vmcnt: global->reg prefetch
// stays in flight across it. Components only in proven form (m201; rule #18).
#define BAR()                                              \
    do {                                                   \
        __builtin_amdgcn_sched_barrier(0);                 \
        asm volatile("s_waitcnt lgkmcnt(0)" ::: "memory"); \
        __builtin_amdgcn_s_barrier();                      \
        __builtin_amdgcn_sched_barrier(0);                 \
    } while (0)

__global__ __launch_bounds__(512, 2) void cov_kernel(const float* __restrict__ X,
                                                     float* __restrict__ out) {
    // Staging: [A/B][buf 0/1][half 0/1][128*32 bf16]  = 64 KB.
    // Epilogue overlay: red[4][64*65] + rs[4*64] + cs[4*64] floats = 68.6 KB.
    __shared__ __align__(16) unsigned char smem[68608];
    __bf16* sAB  = (__bf16*)smem;
    float*  redF = (float*)smem;

    const int bid  = blockIdx.x;          // 192 blocks
    const int xcd  = bid & 7;
    const int g    = bid >> 3;            // 0..23
    const int b    = xcd + 8 * (g / 3);   // a batch's 3 blocks share an XCD
    const int qi   = g % 3;               // 0:(0,0)  1:(1,1)  2:(0,1)+(1,0)^T
    const int row0 = (qi == 1) ? 128 : 0;
    const int col0 = (qi == 0) ? 0 : 128;
    const bool diag = (qi != 2);

    const float* __restrict__ Xb = X + (size_t)b * (NC * NT);

    const int t    = threadIdx.x;        // 512 threads = 8 waves
    const int lane = t & 63;
    const int wave = t >> 6;
    const int h    = wave >> 2;          // K-half: [h*1024, h*1024+1024)
    const int wq   = wave & 3;
    const int wm   = wq >> 1, wn = wq & 1;   // 2x2 waves, 64x64 each
    const int quad = lane >> 4;
    const int l16  = lane & 15;

    // Staging: u = t&255 within half h. Thread u: rows sr and sr+64, k-chunk sc.
    const int u  = t & 255;
    const int sr = u >> 2;               // 0..63
    const int sc = (u & 3) * 8;          // 4 lanes cover 32 contiguous floats/row
    const float* gA0 = Xb + (size_t)(row0 + sr) * NT + h * (NT / 2) + sc;
    const float* gA1 = gA0 + (size_t)64 * NT;
    const float* gB0 = Xb + (size_t)(col0 + sr) * NT + h * (NT / 2) + sc;
    const float* gB1 = gB0 + (size_t)64 * NT;

    // LDS staging bases (elements) for this thread's half.
    __bf16* sA[2] = { sAB + (0 * 2 + h) * 4096, sAB + (1 * 2 + h) * 4096 };
    __bf16* sB[2];
    if (diag) { sB[0] = sA[0]; sB[1] = sA[1]; }     // B-panel == A-panel
    else {
        sB[0] = sAB + 16384 + (0 * 2 + h) * 4096;
        sB[1] = sAB + 16384 + (1 * 2 + h) * 4096;
    }
    const int woff = sr * 32 + sc;       // write offset; second row at +2048

    f32x4 acc[4][4], accRS[4], accCS[4];
#pragma unroll
    for (int i = 0; i < 4; ++i) {
        accRS[i] = (f32x4){0.f, 0.f, 0.f, 0.f};
        accCS[i] = (f32x4){0.f, 0.f, 0.f, 0.f};
#pragma unroll
        for (int j = 0; j < 4; ++j) acc[i][j] = (f32x4){0.f, 0.f, 0.f, 0.f};
    }
    const bf16x8 ones = {(__bf16)1.0f, (__bf16)1.0f, (__bf16)1.0f, (__bf16)1.0f,
                         (__bf16)1.0f, (__bf16)1.0f, (__bf16)1.0f, (__bf16)1.0f};

    // Prologue: issue ALL loads first (iter0 + p=iter1 + q=iter2), then stage
    // iter0 (counted vmcnt waits only the oldest set; p,q stay in flight).
    f32x8 sA0v = *(const f32x8*)gA0;
    f32x8 sA1v = *(const f32x8*)gA1;
    f32x8 sB0v = sA0v, sB1v = sA1v;
    f32x8 pA0, pA1, pB0, pB1, qA0, qA1, qB0, qB1;
    if (!diag) { sB0v = *(const f32x8*)gB0; sB1v = *(const f32x8*)gB1; }
    pA0 = *(const f32x8*)(gA0 + 32);
    pA1 = *(const f32x8*)(gA1 + 32);
    if (!diag) {
        pB0 = *(const f32x8*)(gB0 + 32);
        pB1 = *(const f32x8*)(gB1 + 32);
    }
    qA0 = *(const f32x8*)(gA0 + 64);
    qA1 = *(const f32x8*)(gA1 + 64);
    if (!diag) {
        qB0 = *(const f32x8*)(gB0 + 64);
        qB1 = *(const f32x8*)(gB1 + 64);
    }
    *(bf16x8*)(sA[0] + woff)        = __builtin_convertvector(sA0v, bf16x8);
    *(bf16x8*)(sA[0] + woff + 2048) = __builtin_convertvector(sA1v, bf16x8);
    if (!diag) {
        *(bf16x8*)(sB[0] + woff)        = __builtin_convertvector(sB0v, bf16x8);
        *(bf16x8*)(sB[0] + woff + 2048) = __builtin_convertvector(sB1v, bf16x8);
    }
    BAR();

    const int aBase = (wm * 64 + l16) * 32 + quad * 8;   // + mt*16*32
    const int bBase = (wn * 64 + l16) * 32 + quad * 8;

#pragma unroll 2
    for (int k = 0; k < NITER; ++k) {
        const int cur = k & 1, nxt = cur ^ 1;

        // Stage data for iter k+1 from p (loaded 2 iterations ago -> the
        // compiler's counted vmcnt here does not touch q's in-flight loads).
        if (k + 1 < NITER) {
            *(bf16x8*)(sA[nxt] + woff)        = __builtin_convertvector(pA0, bf16x8);
            *(bf16x8*)(sA[nxt] + woff + 2048) = __builtin_convertvector(pA1, bf16x8);
            if (!diag) {
                *(bf16x8*)(sB[nxt] + woff)        = __builtin_convertvector(pB0, bf16x8);
                *(bf16x8*)(sB[nxt] + woff + 2048) = __builtin_convertvector(pB1, bf16x8);
            }
        }
        // Rotate and issue loads for iter k+3 (2-deep pipeline; unroll 2
        // renames p/q so the copies vanish).
        pA0 = qA0; pA1 = qA1;
        if (!diag) { pB0 = qB0; pB1 = qB1; }
        if (k + 3 < NITER) {
            qA0 = *(const f32x8*)(gA0 + (k + 3) * 32);
            qA1 = *(const f32x8*)(gA1 + (k + 3) * 32);
            if (!diag) {
                qB0 = *(const f32x8*)(gB0 + (k + 3) * 32);
                qB1 = *(const f32x8*)(gB1 + (k + 3) * 32);
            }
        }

        bf16x8 aF[4], bF[4];
#pragma unroll
        for (int mt = 0; mt < 4; ++mt)
            aF[mt] = *(const bf16x8*)(sA[cur] + aBase + mt * 16 * 32);
#pragma unroll
        for (int nt = 0; nt < 4; ++nt)
            bF[nt] = *(const bf16x8*)(sB[cur] + bBase + nt * 16 * 32);

#pragma unroll
        for (int mt = 0; mt < 4; ++mt) {
            accRS[mt] = __builtin_amdgcn_mfma_f32_16x16x32_bf16(aF[mt], ones, accRS[mt], 0, 0, 0);
#pragma unroll
            for (int nt = 0; nt < 4; ++nt)
                acc[mt][nt] = __builtin_amdgcn_mfma_f32_16x16x32_bf16(aF[mt], bF[nt], acc[mt][nt], 0, 0, 0);
        }
#pragma unroll
        for (int nt = 0; nt < 4; ++nt)
            accCS[nt] = __builtin_amdgcn_mfma_f32_16x16x32_bf16(ones, bF[nt], accCS[nt], 0, 0, 0);

        BAR();   // lgkm-only: global prefetch survives the barrier
    }

    // Epilogue: combine the two K-halves. h=1 dumps to LDS; h=0 reduces+stores.
    float* red = redF + wq * (64 * 65);
    float* rs  = redF + 4 * (64 * 65);       // [4][64]
    float* cs  = rs + 256;                   // [4][64]

    if (h == 1) {
#pragma unroll
        for (int mt = 0; mt < 4; ++mt)
#pragma unroll
            for (int nt = 0; nt < 4; ++nt)
#pragma unroll
                for (int r = 0; r < 4; ++r)
                    red[(mt * 16 + quad * 4 + r) * 65 + nt * 16 + l16] = acc[mt][nt][r];
        if (l16 == 0) {
#pragma unroll
            for (int mt = 0; mt < 4; ++mt)
#pragma unroll
                for (int r = 0; r < 4; ++r)
                    rs[wq * 64 + mt * 16 + quad * 4 + r] = accRS[mt][r];
        }
        if (quad == 0) {
#pragma unroll
            for (int nt = 0; nt < 4; ++nt)
                cs[wq * 64 + nt * 16 + l16] = accCS[nt][0];
        }
    }
    __syncthreads();

    const float invT = 1.0f / NT;
    float* __restrict__ outB = out + (size_t)b * (NC * NC);

    if (h == 0) {
#pragma unroll
        for (int mt = 0; mt < 4; ++mt) {
#pragma unroll
            for (int nt = 0; nt < 4; ++nt) {
#pragma unroll
                for (int r = 0; r < 4; ++r) {
                    const int R = mt * 16 + quad * 4 + r;
                    const int C = nt * 16 + l16;
                    const float tot = red[R * 65 + C] + acc[mt][nt][r];
                    const float Sx  = rs[wq * 64 + R] + accRS[mt][r];
                    const float Sy  = cs[wq * 64 + C] + accCS[nt][0];
                    const float val = (tot - Sx * Sy * invT) * invT;
                    outB[(size_t)(row0 + wm * 64 + R) * NC + (col0 + wn * 64 + C)] = val;
                    if (qi == 2) red[R * 65 + C] = val;   // park for transpose
                }
            }
        }
    }

    if (qi == 2) {
        // Mirror the corrected tile into quadrant (1,0): out[col][row] = val.
        __syncthreads();
        if (h == 1) {
#pragma unroll
            for (int mt = 0; mt < 4; ++mt) {
                const int jj = mt * 16 + quad * 4;       // + r
#pragma unroll
                for (int nt = 0; nt < 4; ++nt) {
                    const int ii = nt * 16 + l16;
#pragma unroll
                    for (int r = 0; r < 4; ++r)
                        outB[(size_t)(col0 + wn * 64 + jj + r) * NC +
                             (row0 + wm * 64 + ii)] = red[ii * 65 + jj + r];
                }
            }
        }
    }
}

extern "C" void kernel_launch(void* const* d_in, const int* in_sizes, int n_in,
                              void* d_out, int out_size, void* d_ws, size_t ws_size,
                              hipStream_t stream) {
    const float* X = (const float*)d_in[0];
    float* out = (float*)d_out;
    (void)in_sizes; (void)n_in; (void)out_size; (void)d_ws; (void)ws_size;
    cov_kernel<<<192, 512, 0, stream>>>(X, out);
}